// Round 4
// baseline (389.298 us; speedup 1.0000x reference)
//
#include <hip/hip_runtime.h>
#include <math.h>

// WaveletKANClassifier, MI355X gfx950. fp32 I/O, bf16 MFMA compute.
//
// Round-4: round-3's fused-LN 64x768 tile forced 96 acc VGPRs -> ~204
// regs/wave -> 2 waves/SIMD -> 1 block/CU -> latency-bound (MfmaUtil 11%,
// Occupancy 18.8%). Fix: unfuse LN.
//   K0 pack: W, Wp(hi/lo), Wc -> fragment-major bf16 in d_ws (round-3 code).
//   K1 wav:  wi = x@Wp^T (split-bf16 3-MFMA, fp64 haar boundary recheck),
//            wav = gelu(wavelet(s)) bf16 -> d_ws.  256 thr / 4 waves / 64 rows.
//   K2 gemm: h = x@W^T + wav@Wc^T + b + bc, 128x128 tiles, 4 waves x (64x64),
//            acc=64 VGPR -> 3-4 waves/SIMD co-resident. h written to d_out.
//   K3 ln:   LayerNorm in-place on d_out, one wave per row (12 f32/lane).

#define B_SZ  32768
#define DIN   768
#define DOUT  768
#define NWAV  48

// d_ws layout (units: shorts). Fragment tile = 64 lanes x 8 bf16 = 512
// shorts; lane L holds M[c0+(L&31)][k0 + (L>>5)*8 + j].
#define WF_OFF   0        // W:  24 cb x 48 kb = 589824
#define WPH_OFF  589824   // Wp hi: 2 ct x 48 kb = 49152
#define WPL_OFF  638976   // Wp lo: 49152
#define WCF_OFF  688128   // Wc: 24 cb x 3 kb = 36864
#define WAV_OFF  724992   // wav bf16 [32768 x 48] = 1572864  (total 4.6 MB)

typedef short bf16x8 __attribute__((ext_vector_type(8)));
typedef float f32x16 __attribute__((ext_vector_type(16)));

__device__ __forceinline__ float bf2f(short u) {
    union { unsigned int i; float f; } v;
    v.i = ((unsigned int)(unsigned short)u) << 16;
    return v.f;
}
__device__ __forceinline__ short f2bf(float f) {
    union { float f; unsigned int i; } v; v.f = f;
    unsigned int r = v.i + 0x7FFFu + ((v.i >> 16) & 1u);  // RNE
    return (short)(r >> 16);
}

// ---------------------------------------------------------------- K0: pack
// 1320 fragment tiles: [0,1152) W, [1152,1248) Wp hi+lo, [1248,1320) Wc.
__global__ __launch_bounds__(256) void pack_kernel(
    const float* __restrict__ W, const float* __restrict__ Wp,
    const float* __restrict__ Wc, short* __restrict__ ws)
{
    const int gw = (blockIdx.x * 256 + threadIdx.x) >> 6;
    const int L  = threadIdx.x & 63;
    const int lm = L & 31, half = L >> 5;

    if (gw < 1152) {                       // W [768 x 768]
        const int cb = gw / 48, kb = gw % 48;
        const int row = cb * 32 + lm;
        const int k = kb * 16 + half * 8;
        bf16x8 o;
#pragma unroll
        for (int j = 0; j < 8; j++) o[j] = f2bf(W[(size_t)row * DIN + k + j]);
        *reinterpret_cast<bf16x8*>(&ws[WF_OFF + (size_t)gw * 512 + L * 8]) = o;
    } else if (gw < 1248) {                // Wp [48 x 768], hi/lo, pad rows->64
        const int t = gw - 1152;
        const int ct = t / 48, kb = t % 48;
        const int j = ct * 32 + lm;
        const int k = kb * 16 + half * 8;
        bf16x8 h, l;
#pragma unroll
        for (int jj = 0; jj < 8; jj++) {
            float v = (j < NWAV) ? Wp[(size_t)j * DIN + k + jj] : 0.f;
            const short hh = f2bf(v);
            h[jj] = hh;
            l[jj] = f2bf(v - bf2f(hh));
        }
        *reinterpret_cast<bf16x8*>(&ws[WPH_OFF + (size_t)t * 512 + L * 8]) = h;
        *reinterpret_cast<bf16x8*>(&ws[WPL_OFF + (size_t)t * 512 + L * 8]) = l;
    } else if (gw < 1320) {                // Wc [768 x 48]
        const int t = gw - 1248;
        const int cb = t / 3, kb = t % 3;
        const int row = cb * 32 + lm;
        const int k = kb * 16 + half * 8;
        bf16x8 o;
#pragma unroll
        for (int jj = 0; jj < 8; jj++) o[jj] = f2bf(Wc[(size_t)row * NWAV + k + jj]);
        *reinterpret_cast<bf16x8*>(&ws[WCF_OFF + (size_t)t * 512 + L * 8]) = o;
    }
}

// ---------------------------------------------------------------- K1: wav
__global__ __launch_bounds__(256) void wav_kernel(
    const float* __restrict__ x, const float* __restrict__ Wp,
    const float* __restrict__ bp, const float* __restrict__ sc,
    const float* __restrict__ tr, short* __restrict__ ws)
{
    __shared__ __align__(16) short xh[64 * 72];
    __shared__ __align__(16) short xl[64 * 72];

    const short* WPH = ws + WPH_OFF;
    const short* WPL = ws + WPL_OFF;
    short* wav = ws + WAV_OFF;

    const int tid = threadIdx.x;
    const int r0  = blockIdx.x * 64;
    const int wv  = tid >> 6, L = tid & 63;
    const int lm  = L & 31, half = L >> 5;
    const int rt  = wv & 1, ct = wv >> 1;   // wave tile: rows rt*32.., cols ct*32..

    f32x16 wacc;
#pragma unroll
    for (int g = 0; g < 16; g++) wacc[g] = 0.f;

    const int srow = tid >> 2;
    const int sk   = (tid & 3) * 16;   // 16 f32 per thread

    for (int k0i = 0; k0i < 12; ++k0i) {
        const float4* xp = reinterpret_cast<const float4*>(
            &x[(size_t)(r0 + srow) * DIN + k0i * 64 + sk]);
        const float4 v0 = xp[0], v1 = xp[1], v2 = xp[2], v3 = xp[3];
        __syncthreads();   // prior compute done before overwrite
        {
            const float f[16] = {v0.x, v0.y, v0.z, v0.w, v1.x, v1.y, v1.z, v1.w,
                                 v2.x, v2.y, v2.z, v2.w, v3.x, v3.y, v3.z, v3.w};
            bf16x8 hh0, ll0, hh1, ll1;
#pragma unroll
            for (int i = 0; i < 8; i++) {
                short h = f2bf(f[i]);
                hh0[i] = h; ll0[i] = f2bf(f[i] - bf2f(h));
                h = f2bf(f[8 + i]);
                hh1[i] = h; ll1[i] = f2bf(f[8 + i] - bf2f(h));
            }
            *reinterpret_cast<bf16x8*>(&xh[srow * 72 + sk])     = hh0;
            *reinterpret_cast<bf16x8*>(&xh[srow * 72 + sk + 8]) = hh1;
            *reinterpret_cast<bf16x8*>(&xl[srow * 72 + sk])     = ll0;
            *reinterpret_cast<bf16x8*>(&xl[srow * 72 + sk + 8]) = ll1;
        }
        __syncthreads();
        const int kb0 = k0i * 4;
#pragma unroll
        for (int ks = 0; ks < 4; ++ks) {
            const bf16x8 ah = *reinterpret_cast<bf16x8*>(&xh[(rt * 32 + lm) * 72 + ks * 16 + half * 8]);
            const bf16x8 al = *reinterpret_cast<bf16x8*>(&xl[(rt * 32 + lm) * 72 + ks * 16 + half * 8]);
            const bf16x8 bh = *reinterpret_cast<const bf16x8*>(&WPH[((size_t)(ct * 48 + kb0 + ks)) * 512 + L * 8]);
            const bf16x8 bl = *reinterpret_cast<const bf16x8*>(&WPL[((size_t)(ct * 48 + kb0 + ks)) * 512 + L * 8]);
            wacc = __builtin_amdgcn_mfma_f32_32x32x16_bf16(ah, bl, wacc, 0, 0, 0);
            wacc = __builtin_amdgcn_mfma_f32_32x32x16_bf16(al, bh, wacc, 0, 0, 0);
            wacc = __builtin_amdgcn_mfma_f32_32x32x16_bf16(ah, bh, wacc, 0, 0, 0);
        }
    }

    // epilogue: wavelet + GELU -> wav (bf16)
    const int j = ct * 32 + lm;
    if (j < NWAV) {
        const float bpv = bp[j], scv = sc[j], trv = tr[j];
#pragma unroll
        for (int g = 0; g < 16; ++g) {
            const int rowl = rt * 32 + (g & 3) + 8 * (g >> 2) + 4 * half;  // C/D map
            const float wi = wacc[g] + bpv;
            const float s = (wi - trv) / scv;
            float w;
            if (j < 16) {
                const float dmin = fminf(fabsf(s), fminf(fabsf(s - 0.5f), fabsf(s - 1.0f)));
                if (dmin < 2e-4f) {   // fp64 recheck at the step boundary
                    const float* xr = &x[(size_t)(r0 + rowl) * DIN];
                    const float* wr = &Wp[(size_t)j * DIN];
                    double a0 = 0.0, a1 = 0.0, a2 = 0.0, a3 = 0.0;
                    for (int k = 0; k < DIN; k += 4) {
                        a0 = fma((double)xr[k + 0], (double)wr[k + 0], a0);
                        a1 = fma((double)xr[k + 1], (double)wr[k + 1], a1);
                        a2 = fma((double)xr[k + 2], (double)wr[k + 2], a2);
                        a3 = fma((double)xr[k + 3], (double)wr[k + 3], a3);
                    }
                    const double wid = ((a0 + a1) + (a2 + a3)) + (double)bpv;
                    const double sd = (wid - (double)trv) / (double)scv;
                    w = (sd >= 0.0 && sd < 0.5) ? 1.f : ((sd >= 0.5 && sd < 1.0) ? -1.f : 0.f);
                } else {
                    w = (s >= 0.f && s < 0.5f) ? 1.f : ((s >= 0.5f && s < 1.f) ? -1.f : 0.f);
                }
            } else if (j < 32) {
                w = (1.f - s * s) * expf(-0.5f * s * s);
            } else {
                w = cosf(5.f * s) * expf(-0.5f * s * s);
            }
            const float gel = 0.5f * w * (1.f + erff(w * 0.70710678118654752f));
            wav[(size_t)(r0 + rowl) * NWAV + j] = f2bf(gel);
        }
    }
}

// ---------------------------------------------------------------- K2: gemm
// h = x@W^T + wav@Wc^T + (b+bc)  -> d_out (fp32). 128x128 tile, 4 waves.
__global__ __launch_bounds__(256, 3) void gemm_kernel(
    const float* __restrict__ x, const short* __restrict__ ws,
    const float* __restrict__ bb, const float* __restrict__ bc,
    float* __restrict__ hout)
{
    __shared__ __align__(16) short xs[2][128 * 72];

    const short* WF  = ws + WF_OFF;
    const short* WCF = ws + WCF_OFF;
    const short* wavg = ws + WAV_OFF;

    const int tid  = threadIdx.x;
    const int bx   = blockIdx.x;
    const int colb = bx % 6;             // 128-col block
    const int r0   = (bx / 6) * 128;
    const int wv   = tid >> 6, L = tid & 63;
    const int lm   = L & 31, half = L >> 5;
    const int wm   = wv >> 1, wn = wv & 1;   // wave = rows wm*64.., cols wn*64..

    f32x16 acc[2][2];
#pragma unroll
    for (int rt = 0; rt < 2; rt++)
#pragma unroll
        for (int ct = 0; ct < 2; ct++)
#pragma unroll
            for (int g = 0; g < 16; g++) acc[rt][ct][g] = 0.f;

    const int srow = tid >> 1;           // 0..127
    const int sk   = (tid & 1) * 32;     // 32 f32 per thread

    // prologue: stage k-chunk 0 into buf 0
    {
        const float4* xp = reinterpret_cast<const float4*>(&x[(size_t)(r0 + srow) * DIN + sk]);
#pragma unroll
        for (int u = 0; u < 4; ++u) {
            const float4 a = xp[2 * u], b2 = xp[2 * u + 1];
            bf16x8 hh;
            hh[0] = f2bf(a.x); hh[1] = f2bf(a.y); hh[2] = f2bf(a.z); hh[3] = f2bf(a.w);
            hh[4] = f2bf(b2.x); hh[5] = f2bf(b2.y); hh[6] = f2bf(b2.z); hh[7] = f2bf(b2.w);
            *reinterpret_cast<bf16x8*>(&xs[0][srow * 72 + sk + u * 8]) = hh;
        }
    }
    __syncthreads();

    for (int k0i = 0; k0i < 12; ++k0i) {
        const int cur = k0i & 1;
        float4 pf[8];
        if (k0i < 11) {
            const float4* xp = reinterpret_cast<const float4*>(
                &x[(size_t)(r0 + srow) * DIN + (k0i + 1) * 64 + sk]);
#pragma unroll
            for (int u = 0; u < 8; ++u) pf[u] = xp[u];
        }
        const int kb0 = k0i * 4;
#pragma unroll
        for (int ks = 0; ks < 4; ++ks) {
            const bf16x8 a0 = *reinterpret_cast<bf16x8*>(&xs[cur][(wm * 64 + lm) * 72 + ks * 16 + half * 8]);
            const bf16x8 a1 = *reinterpret_cast<bf16x8*>(&xs[cur][(wm * 64 + 32 + lm) * 72 + ks * 16 + half * 8]);
#pragma unroll
            for (int ct = 0; ct < 2; ++ct) {
                const int cb = colb * 4 + wn * 2 + ct;
                const bf16x8 b = *reinterpret_cast<const bf16x8*>(
                    &WF[((size_t)(cb * 48 + kb0 + ks)) * 512 + L * 8]);
                acc[0][ct] = __builtin_amdgcn_mfma_f32_32x32x16_bf16(a0, b, acc[0][ct], 0, 0, 0);
                acc[1][ct] = __builtin_amdgcn_mfma_f32_32x32x16_bf16(a1, b, acc[1][ct], 0, 0, 0);
            }
        }
        if (k0i < 11) {
#pragma unroll
            for (int u = 0; u < 4; ++u) {
                const float4 a = pf[2 * u], b2 = pf[2 * u + 1];
                bf16x8 hh;
                hh[0] = f2bf(a.x); hh[1] = f2bf(a.y); hh[2] = f2bf(a.z); hh[3] = f2bf(a.w);
                hh[4] = f2bf(b2.x); hh[5] = f2bf(b2.y); hh[6] = f2bf(b2.z); hh[7] = f2bf(b2.w);
                *reinterpret_cast<bf16x8*>(&xs[1 - cur][srow * 72 + sk + u * 8]) = hh;
            }
        }
        __syncthreads();
    }

    // ---- wav tile: 128 rows x 48 (zero-pad to 64) into xs[0]
    {
        const int row = tid >> 1, part = tid & 1;
        const int4* src = reinterpret_cast<const int4*>(&wavg[(size_t)(r0 + row) * NWAV + part * 24]);
        const int4 a = src[0], b2 = src[1], c = src[2];
        int4* dst = reinterpret_cast<int4*>(&xs[0][row * 72 + part * 24]);
        dst[0] = a; dst[1] = b2; dst[2] = c;
        const int4 zz = {0, 0, 0, 0};
        *reinterpret_cast<int4*>(&xs[0][row * 72 + 48 + part * 8]) = zz;
    }
    __syncthreads();
#pragma unroll
    for (int ks = 0; ks < 3; ++ks) {
        const bf16x8 a0 = *reinterpret_cast<bf16x8*>(&xs[0][(wm * 64 + lm) * 72 + ks * 16 + half * 8]);
        const bf16x8 a1 = *reinterpret_cast<bf16x8*>(&xs[0][(wm * 64 + 32 + lm) * 72 + ks * 16 + half * 8]);
#pragma unroll
        for (int ct = 0; ct < 2; ++ct) {
            const int cb = colb * 4 + wn * 2 + ct;
            const bf16x8 b = *reinterpret_cast<const bf16x8*>(
                &WCF[((size_t)(cb * 3 + ks)) * 512 + L * 8]);
            acc[0][ct] = __builtin_amdgcn_mfma_f32_32x32x16_bf16(a0, b, acc[0][ct], 0, 0, 0);
            acc[1][ct] = __builtin_amdgcn_mfma_f32_32x32x16_bf16(a1, b, acc[1][ct], 0, 0, 0);
        }
    }

    // ---- bias + store h (fp32) to d_out
#pragma unroll
    for (int ct = 0; ct < 2; ++ct) {
        const int colg = (colb * 4 + wn * 2 + ct) * 32 + lm;
        const float bias = bb[colg] + bc[colg];
#pragma unroll
        for (int rt = 0; rt < 2; ++rt) {
#pragma unroll
            for (int g = 0; g < 16; ++g) {
                const int row = r0 + wm * 64 + rt * 32 + (g & 3) + 8 * (g >> 2) + 4 * half;
                hout[(size_t)row * DOUT + colg] = acc[rt][ct][g] + bias;
            }
        }
    }
}

// ---------------------------------------------------------------- K3: LN
// In-place LayerNorm on d_out. One wave per row; 12 f32/lane.
__global__ __launch_bounds__(256) void ln_kernel(
    float* __restrict__ io, const float* __restrict__ gm,
    const float* __restrict__ bt)
{
    const int row = blockIdx.x * 4 + (threadIdx.x >> 6);
    const int l   = threadIdx.x & 63;
    float* rp = &io[(size_t)row * DOUT];

    float4 v[3];
#pragma unroll
    for (int c = 0; c < 3; ++c)
        v[c] = *reinterpret_cast<const float4*>(&rp[l * 4 + c * 256]);

    float s1 = 0.f, s2 = 0.f;
#pragma unroll
    for (int c = 0; c < 3; ++c) {
        s1 += v[c].x + v[c].y + v[c].z + v[c].w;
        s2 += v[c].x * v[c].x + v[c].y * v[c].y + v[c].z * v[c].z + v[c].w * v[c].w;
    }
#pragma unroll
    for (int d = 1; d < 64; d <<= 1) {
        s1 += __shfl_xor(s1, d);
        s2 += __shfl_xor(s2, d);
    }
    const float mu = s1 * (1.f / 768.f);
    const float rs = rsqrtf(s2 * (1.f / 768.f) - mu * mu + 1e-5f);

#pragma unroll
    for (int c = 0; c < 3; ++c) {
        const float4 g = *reinterpret_cast<const float4*>(&gm[l * 4 + c * 256]);
        const float4 b = *reinterpret_cast<const float4*>(&bt[l * 4 + c * 256]);
        float4 o;
        o.x = (v[c].x - mu) * rs * g.x + b.x;
        o.y = (v[c].y - mu) * rs * g.y + b.y;
        o.z = (v[c].z - mu) * rs * g.z + b.z;
        o.w = (v[c].w - mu) * rs * g.w + b.w;
        *reinterpret_cast<float4*>(&rp[l * 4 + c * 256]) = o;
    }
}

// ---------------------------------------------------------------- launcher
extern "C" void kernel_launch(void* const* d_in, const int* in_sizes, int n_in,
                              void* d_out, int out_size, void* d_ws, size_t ws_size,
                              hipStream_t stream)
{
    const float* x  = (const float*)d_in[0];
    const float* W  = (const float*)d_in[1];
    const float* b  = (const float*)d_in[2];
    const float* Wp = (const float*)d_in[3];
    const float* bp = (const float*)d_in[4];
    const float* Wc = (const float*)d_in[5];
    const float* bc = (const float*)d_in[6];
    const float* sc = (const float*)d_in[7];
    const float* tr = (const float*)d_in[8];
    const float* gm = (const float*)d_in[9];
    const float* bt = (const float*)d_in[10];
    float* out = (float*)d_out;
    short* ws  = (short*)d_ws;   // 4.6 MB: fragment weights + wav

    pack_kernel<<<dim3(330), dim3(256), 0, stream>>>(W, Wp, Wc, ws);
    wav_kernel<<<dim3(B_SZ / 64), dim3(256), 0, stream>>>(x, Wp, bp, sc, tr, ws);
    gemm_kernel<<<dim3((B_SZ / 128) * 6), dim3(256), 0, stream>>>(x, ws, b, bc, out);
    ln_kernel<<<dim3(B_SZ / 4), dim3(256), 0, stream>>>(out, gm, bt);
}

// Round 5
// 309.325 us; speedup vs baseline: 1.2585x; 1.2585x over previous
//
#include <hip/hip_runtime.h>
#include <math.h>

// WaveletKANClassifier, MI355X gfx950. fp32 I/O, bf16 MFMA compute.
//
// Round-5: fused full-width block (round-3 cache behavior: FETCH 62 MB vs
// round-4's 310 MB) with fixed occupancy (round-3 fail: 96 acc -> 2
// waves/SIMD). Block = 64 rows x 768 cols, 1024 thr = 16 waves, wave =
// 32r x 96c -> acc 48/lane -> ~115 regs -> 4 waves/SIMD.
// wi = x@Wp^T is K-split 4x across waves (kq = wv>>2; one wave per kq per
// SIMD -> balanced MFMA issue), partials reduced via LDS overlay.
// LN fused; out written once; no h/wav HBM round-trips.

#define B_SZ  32768
#define DIN   768
#define DOUT  768
#define NWAV  48

// d_ws fragment-major layout (units: shorts). Tile = 64 lanes x 8 bf16 =
// 512 shorts; lane L holds M[cb*32+(L&31)][kb*16 + (L>>5)*8 + j].
#define WF_OFF   0        // W:  24 cb x 48 kb = 589824
#define WPH_OFF  589824   // Wp hi: 2 ct x 48 kb = 49152
#define WPL_OFF  638976   // Wp lo: 49152
#define WCF_OFF  688128   // Wc: 24 cb x 3 kb = 36864   (total 724992 sh)

typedef short bf16x8 __attribute__((ext_vector_type(8)));
typedef float f32x16 __attribute__((ext_vector_type(16)));

__device__ __forceinline__ float bf2f(short u) {
    union { unsigned int i; float f; } v;
    v.i = ((unsigned int)(unsigned short)u) << 16;
    return v.f;
}
__device__ __forceinline__ short f2bf(float f) {
    union { float f; unsigned int i; } v; v.f = f;
    unsigned int r = v.i + 0x7FFFu + ((v.i >> 16) & 1u);  // RNE
    return (short)(r >> 16);
}

// ---------------------------------------------------------------- K0: pack
// 1320 fragment tiles: [0,1152) W, [1152,1248) Wp hi+lo, [1248,1320) Wc.
__global__ __launch_bounds__(256) void pack_kernel(
    const float* __restrict__ W, const float* __restrict__ Wp,
    const float* __restrict__ Wc, short* __restrict__ ws)
{
    const int gw = (blockIdx.x * 256 + threadIdx.x) >> 6;
    const int L  = threadIdx.x & 63;
    const int lm = L & 31, half = L >> 5;

    if (gw < 1152) {                       // W [768 x 768]
        const int cb = gw / 48, kb = gw % 48;
        const int row = cb * 32 + lm;
        const int k = kb * 16 + half * 8;
        bf16x8 o;
#pragma unroll
        for (int j = 0; j < 8; j++) o[j] = f2bf(W[(size_t)row * DIN + k + j]);
        *reinterpret_cast<bf16x8*>(&ws[WF_OFF + (size_t)gw * 512 + L * 8]) = o;
    } else if (gw < 1248) {                // Wp [48 x 768], hi/lo, pad rows->64
        const int t = gw - 1152;
        const int ct = t / 48, kb = t % 48;
        const int j = ct * 32 + lm;
        const int k = kb * 16 + half * 8;
        bf16x8 h, l;
#pragma unroll
        for (int jj = 0; jj < 8; jj++) {
            float v = (j < NWAV) ? Wp[(size_t)j * DIN + k + jj] : 0.f;
            const short hh = f2bf(v);
            h[jj] = hh;
            l[jj] = f2bf(v - bf2f(hh));
        }
        *reinterpret_cast<bf16x8*>(&ws[WPH_OFF + (size_t)t * 512 + L * 8]) = h;
        *reinterpret_cast<bf16x8*>(&ws[WPL_OFF + (size_t)t * 512 + L * 8]) = l;
    } else if (gw < 1320) {                // Wc [768 x 48]
        const int t = gw - 1248;
        const int cb = t / 3, kb = t % 3;
        const int row = cb * 32 + lm;
        const int k = kb * 16 + half * 8;
        bf16x8 o;
#pragma unroll
        for (int jj = 0; jj < 8; jj++) o[jj] = f2bf(Wc[(size_t)row * NWAV + k + jj]);
        *reinterpret_cast<bf16x8*>(&ws[WCF_OFF + (size_t)t * 512 + L * 8]) = o;
    }
}

// ---------------------------------------------------------------- K1: fused
__global__ __launch_bounds__(1024) void fused_kernel(
    const float* __restrict__ x, const short* __restrict__ ws,
    const float* __restrict__ Wp,
    const float* __restrict__ bp, const float* __restrict__ sc,
    const float* __restrict__ tr,
    const float* __restrict__ bb, const float* __restrict__ bc,
    const float* __restrict__ gm, const float* __restrict__ bt,
    float* __restrict__ out)
{
    // xbuf: xh[2][64*72] ++ xl[2][64*72] = 73728 shorts (36.9 KB).
    // After the K loop it is dead and overlaid by wiS[2][64][64] f32 (32 KB).
    __shared__ __align__(16) short xbuf[73728];
    __shared__ __align__(16) short wavL[64 * 72];           // 9.2 KB
    __shared__ float redS[64 * 8], redQ[64 * 8];            // 4 KB
    __shared__ float muA[64], rsA[64];

    short (*xh)[64 * 72] = reinterpret_cast<short (*)[64 * 72]>(&xbuf[0]);
    short (*xl)[64 * 72] = reinterpret_cast<short (*)[64 * 72]>(&xbuf[2 * 64 * 72]);
    float* wiS = reinterpret_cast<float*>(&xbuf[0]);        // [2][64][64] f32

    const short* WF  = ws + WF_OFF;
    const short* WPH = ws + WPH_OFF;
    const short* WPL = ws + WPL_OFF;
    const short* WCF = ws + WCF_OFF;

    const int tid = threadIdx.x;
    const int r0  = blockIdx.x * 64;
    const int wv  = tid >> 6, L = tid & 63;
    const int lm  = L & 31, half = L >> 5;
    const int rg  = wv >> 3, cg = wv & 7;    // direct: rows rg*32.., cols cg*96..
    const int kq  = wv >> 2;                 // wi k-quarter (one per SIMD)
    const int wrg = (wv & 3) >> 1, wch = wv & 1;  // wi subtile rows/cols

    f32x16 acc[3];
#pragma unroll
    for (int ct = 0; ct < 3; ct++)
#pragma unroll
        for (int g = 0; g < 16; g++) acc[ct][g] = 0.f;
    f32x16 wacc;
#pragma unroll
    for (int g = 0; g < 16; g++) wacc[g] = 0.f;

    // staging: 64 rows x 64 k f32 per chunk; 4 f32/thread.
    const int srow = tid >> 4;           // 0..63
    const int skc  = (tid & 15) * 4;     // k offset within chunk

    // prologue: stage chunk 0 into buf 0
    {
        const float4 v = *reinterpret_cast<const float4*>(&x[(size_t)(r0 + srow) * DIN + skc]);
        const float f[4] = {v.x, v.y, v.z, v.w};
        short hh[4], ll[4];
#pragma unroll
        for (int i = 0; i < 4; i++) {
            hh[i] = f2bf(f[i]);
            ll[i] = f2bf(f[i] - bf2f(hh[i]));
        }
        *reinterpret_cast<short4*>(&xh[0][srow * 72 + skc]) = *reinterpret_cast<short4*>(hh);
        *reinterpret_cast<short4*>(&xl[0][srow * 72 + skc]) = *reinterpret_cast<short4*>(ll);
    }
    __syncthreads();

    for (int k0i = 0; k0i < 12; ++k0i) {
        const int cur = k0i & 1;
        float4 pf;
        if (k0i < 11)
            pf = *reinterpret_cast<const float4*>(&x[(size_t)(r0 + srow) * DIN + (k0i + 1) * 64 + skc]);

        const int kb0 = k0i * 4;
        // direct path: 12 MFMA / wave / chunk
#pragma unroll
        for (int ks = 0; ks < 4; ++ks) {
            const bf16x8 a0 = *reinterpret_cast<bf16x8*>(&xh[cur][(rg * 32 + lm) * 72 + ks * 16 + half * 8]);
#pragma unroll
            for (int ct = 0; ct < 3; ++ct) {
                const bf16x8 b = *reinterpret_cast<const bf16x8*>(
                    &WF[((size_t)((cg * 3 + ct) * 48 + kb0 + ks)) * 512 + L * 8]);
                acc[ct] = __builtin_amdgcn_mfma_f32_32x32x16_bf16(a0, b, acc[ct], 0, 0, 0);
            }
        }
        // wi path: only the kq-matching waves this chunk (wave-uniform branch)
        if (k0i >= kq * 3 && k0i < kq * 3 + 3) {
#pragma unroll
            for (int ks = 0; ks < 4; ++ks) {
                const bf16x8 ah = *reinterpret_cast<bf16x8*>(&xh[cur][(wrg * 32 + lm) * 72 + ks * 16 + half * 8]);
                const bf16x8 al = *reinterpret_cast<bf16x8*>(&xl[cur][(wrg * 32 + lm) * 72 + ks * 16 + half * 8]);
                const bf16x8 bh = *reinterpret_cast<const bf16x8*>(
                    &WPH[((size_t)(wch * 48 + kb0 + ks)) * 512 + L * 8]);
                const bf16x8 bl = *reinterpret_cast<const bf16x8*>(
                    &WPL[((size_t)(wch * 48 + kb0 + ks)) * 512 + L * 8]);
                wacc = __builtin_amdgcn_mfma_f32_32x32x16_bf16(ah, bl, wacc, 0, 0, 0);
                wacc = __builtin_amdgcn_mfma_f32_32x32x16_bf16(al, bh, wacc, 0, 0, 0);
                wacc = __builtin_amdgcn_mfma_f32_32x32x16_bf16(ah, bh, wacc, 0, 0, 0);
            }
        }
        if (k0i < 11) {
            const float f[4] = {pf.x, pf.y, pf.z, pf.w};
            short hh[4], ll[4];
#pragma unroll
            for (int i = 0; i < 4; i++) {
                hh[i] = f2bf(f[i]);
                ll[i] = f2bf(f[i] - bf2f(hh[i]));
            }
            *reinterpret_cast<short4*>(&xh[1 - cur][srow * 72 + skc]) = *reinterpret_cast<short4*>(hh);
            *reinterpret_cast<short4*>(&xl[1 - cur][srow * 72 + skc]) = *reinterpret_cast<short4*>(ll);
        }
        __syncthreads();
    }

    // ---- wi partial reduction (xbuf now dead -> wiS overlay, 2 rounds)
    // round 1: kq 0,1 write layer kq; round 2: kq 2,3 add into layer kq-2.
    if (kq < 2) {
#pragma unroll
        for (int g = 0; g < 16; ++g) {
            const int row = wrg * 32 + (g & 3) + 8 * (g >> 2) + 4 * half;
            wiS[(size_t)kq * 4096 + row * 64 + wch * 32 + lm] = wacc[g];
        }
    }
    __syncthreads();
    if (kq >= 2) {
#pragma unroll
        for (int g = 0; g < 16; ++g) {
            const int row = wrg * 32 + (g & 3) + 8 * (g >> 2) + 4 * half;
            wiS[(size_t)(kq - 2) * 4096 + row * 64 + wch * 32 + lm] += wacc[g];
        }
    }
    __syncthreads();

    // ---- wavelet + GELU -> wavL (wave wv: rows wv*4..+3, col = lane)
    const int j = L;
    if (j < NWAV) {
        const float bpv = bp[j], scv = sc[j], trv = tr[j];
#pragma unroll
        for (int rr = 0; rr < 4; ++rr) {
            const int row = wv * 4 + rr;
            const float wi = wiS[row * 64 + j] + wiS[4096 + row * 64 + j] + bpv;
            const float s = (wi - trv) / scv;
            float w;
            if (j < 16) {
                const float dmin = fminf(fabsf(s), fminf(fabsf(s - 0.5f), fabsf(s - 1.0f)));
                if (dmin < 2e-4f) {   // fp64 recheck at the haar step boundary
                    const float* xr = &x[(size_t)(r0 + row) * DIN];
                    const float* wr = &Wp[(size_t)j * DIN];
                    double a0 = 0.0, a1 = 0.0, a2 = 0.0, a3 = 0.0;
                    for (int k = 0; k < DIN; k += 4) {
                        a0 = fma((double)xr[k + 0], (double)wr[k + 0], a0);
                        a1 = fma((double)xr[k + 1], (double)wr[k + 1], a1);
                        a2 = fma((double)xr[k + 2], (double)wr[k + 2], a2);
                        a3 = fma((double)xr[k + 3], (double)wr[k + 3], a3);
                    }
                    const double wid = ((a0 + a1) + (a2 + a3)) + (double)bpv;
                    const double sd = (wid - (double)trv) / (double)scv;
                    w = (sd >= 0.0 && sd < 0.5) ? 1.f : ((sd >= 0.5 && sd < 1.0) ? -1.f : 0.f);
                } else {
                    w = (s >= 0.f && s < 0.5f) ? 1.f : ((s >= 0.5f && s < 1.f) ? -1.f : 0.f);
                }
            } else if (j < 32) {
                w = (1.f - s * s) * expf(-0.5f * s * s);
            } else {
                w = cosf(5.f * s) * expf(-0.5f * s * s);
            }
            const float gel = 0.5f * w * (1.f + erff(w * 0.70710678118654752f));
            wavL[row * 72 + j] = f2bf(gel);
        }
    }
    __syncthreads();

    // ---- h += wav @ Wc^T  (K = 48 = 3 ksteps exactly)
#pragma unroll
    for (int ks = 0; ks < 3; ++ks) {
        const bf16x8 a0 = *reinterpret_cast<bf16x8*>(&wavL[(rg * 32 + lm) * 72 + ks * 16 + half * 8]);
#pragma unroll
        for (int ct = 0; ct < 3; ++ct) {
            const bf16x8 b = *reinterpret_cast<const bf16x8*>(
                &WCF[((size_t)((cg * 3 + ct) * 3 + ks)) * 512 + L * 8]);
            acc[ct] = __builtin_amdgcn_mfma_f32_32x32x16_bf16(a0, b, acc[ct], 0, 0, 0);
        }
    }

    // ---- bias + LN reduction
    float bias[3], g_[3], b_[3];
#pragma unroll
    for (int ct = 0; ct < 3; ++ct) {
        const int col = cg * 96 + ct * 32 + lm;
        bias[ct] = bb[col] + bc[col];
        g_[ct] = gm[col];
        b_[ct] = bt[col];
    }
#pragma unroll
    for (int g = 0; g < 16; ++g) {
        const float v0 = acc[0][g] + bias[0];
        const float v1 = acc[1][g] + bias[1];
        const float v2 = acc[2][g] + bias[2];
        acc[0][g] = v0; acc[1][g] = v1; acc[2][g] = v2;
        float s1 = v0 + v1 + v2;
        float s2 = v0 * v0 + v1 * v1 + v2 * v2;
        s1 += __shfl_xor(s1, 1);  s2 += __shfl_xor(s2, 1);
        s1 += __shfl_xor(s1, 2);  s2 += __shfl_xor(s2, 2);
        s1 += __shfl_xor(s1, 4);  s2 += __shfl_xor(s2, 4);
        s1 += __shfl_xor(s1, 8);  s2 += __shfl_xor(s2, 8);
        s1 += __shfl_xor(s1, 16); s2 += __shfl_xor(s2, 16);
        if (lm == 0) {
            const int row = rg * 32 + (g & 3) + 8 * (g >> 2) + 4 * half;
            redS[row * 8 + cg] = s1;
            redQ[row * 8 + cg] = s2;
        }
    }
    __syncthreads();
    if (tid < 64) {
        float S = 0.f, Q = 0.f;
#pragma unroll
        for (int i = 0; i < 8; i++) { S += redS[tid * 8 + i]; Q += redQ[tid * 8 + i]; }
        const float mu = S * (1.f / 768.f);
        const float var = Q * (1.f / 768.f) - mu * mu;
        muA[tid] = mu;
        rsA[tid] = rsqrtf(var + 1e-5f);
    }
    __syncthreads();

    // ---- normalize + store (f32, written exactly once)
#pragma unroll
    for (int g = 0; g < 16; ++g) {
        const int row = rg * 32 + (g & 3) + 8 * (g >> 2) + 4 * half;
        const float mu = muA[row], rs = rsA[row];
        float* orow = &out[(size_t)(r0 + row) * DOUT + cg * 96 + lm];
#pragma unroll
        for (int ct = 0; ct < 3; ++ct) {
            orow[ct * 32] = (acc[ct][g] - mu) * rs * g_[ct] + b_[ct];
        }
    }
}

// ---------------------------------------------------------------- launcher
extern "C" void kernel_launch(void* const* d_in, const int* in_sizes, int n_in,
                              void* d_out, int out_size, void* d_ws, size_t ws_size,
                              hipStream_t stream)
{
    const float* x  = (const float*)d_in[0];
    const float* W  = (const float*)d_in[1];
    const float* b  = (const float*)d_in[2];
    const float* Wp = (const float*)d_in[3];
    const float* bp = (const float*)d_in[4];
    const float* Wc = (const float*)d_in[5];
    const float* bc = (const float*)d_in[6];
    const float* sc = (const float*)d_in[7];
    const float* tr = (const float*)d_in[8];
    const float* gm = (const float*)d_in[9];
    const float* bt = (const float*)d_in[10];
    float* out = (float*)d_out;
    short* ws  = (short*)d_ws;   // 1.45 MB fragment-packed weights

    pack_kernel<<<dim3(330), dim3(256), 0, stream>>>(W, Wp, Wc, ws);
    fused_kernel<<<dim3(B_SZ / 64), dim3(1024), 0, stream>>>(
        x, ws, Wp, bp, sc, tr, b, bc, gm, bt, out);
}